// Round 11
// baseline (221.001 us; speedup 1.0000x reference)
//
#include <hip/hip_runtime.h>
#include <hip/hip_bf16.h>

typedef unsigned short u16;
typedef __attribute__((ext_vector_type(4))) float f32x4;
typedef __attribute__((ext_vector_type(8))) short bf16x8;

#define SEQ 2048
#define DM 1024
#define DKK 64
#define NH 16
#define DFF 2048
#define TOK 4096

#define AS1 __attribute__((address_space(1)))
#define AS3 __attribute__((address_space(3)))

#define MFMA16(a, b, c) __builtin_amdgcn_mfma_f32_16x16x32_bf16((a), (b), (c), 0, 0, 0)

__device__ __forceinline__ u16 f2b(float f) {
  unsigned u = __float_as_uint(f);
  u = u + 0x7fffu + ((u >> 16) & 1u);
  return (u16)(u >> 16);
}

__device__ __forceinline__ unsigned cvtpk(float lo, float hi) {
  unsigned r;
  asm("v_cvt_pk_bf16_f32 %0, %1, %2" : "=v"(r) : "v"(lo), "v"(hi));
  return r;
}

__device__ __forceinline__ void gload_lds16(const u16* g, u16* l) {
  __builtin_amdgcn_global_load_lds((AS1 unsigned*)(size_t)g, (AS3 unsigned*)l, 16, 0, 0);
}

// ------- fused prep: 6 weight transposes (fp32 [K,N] -> bf16 [N,K]) + LayerNorm1 -------
__global__ __launch_bounds__(256)
void prep_all(const float* __restrict__ Wq, const float* __restrict__ Wk,
              const float* __restrict__ Wv, const float* __restrict__ Wo,
              const float* __restrict__ W1, const float* __restrict__ W2,
              u16* __restrict__ Wqkt, u16* __restrict__ Wvt, u16* __restrict__ Wot,
              u16* __restrict__ W1t, u16* __restrict__ W2t,
              const float* __restrict__ x, const float* __restrict__ alpha,
              const float* __restrict__ beta, u16* __restrict__ xout) {
  __shared__ float t[32][33];
  const int bid = blockIdx.x;
  const int tid = threadIdx.x;
  if (bid < 8192) {  // transpose path
    const float* src;
    u16* dst;
    int K, N, lb;
    if (bid < 1024)      { src = Wq; dst = Wqkt;             K = 1024; N = 1024; lb = bid; }
    else if (bid < 2048) { src = Wk; dst = Wqkt + (1 << 20); K = 1024; N = 1024; lb = bid - 1024; }
    else if (bid < 3072) { src = Wv; dst = Wvt;              K = 1024; N = 1024; lb = bid - 2048; }
    else if (bid < 4096) { src = Wo; dst = Wot;              K = 1024; N = 1024; lb = bid - 3072; }
    else if (bid < 6144) { src = W1; dst = W1t;              K = 1024; N = 2048; lb = bid - 4096; }
    else                 { src = W2; dst = W2t;              K = 2048; N = 1024; lb = bid - 6144; }
    const int nx = N / 32;
    const int n0 = (lb % nx) * 32, k0 = (lb / nx) * 32;
    const int tx = tid & 31, ty = tid >> 5;
#pragma unroll
    for (int i = 0; i < 4; i++) {
      int k = ty + i * 8;
      t[k][tx] = src[(size_t)(k0 + k) * N + n0 + tx];
    }
    __syncthreads();
#pragma unroll
    for (int i = 0; i < 4; i++) {
      int n = ty + i * 8;
      dst[(size_t)(n0 + n) * K + k0 + tx] = f2b(t[tx][n]);
    }
  } else {  // LayerNorm1 path
    const int row = bid - 8192;
    const float4 v = ((const float4*)(x + (size_t)row * DM))[tid];
    float s = v.x + v.y + v.z + v.w;
    float q = v.x * v.x + v.y * v.y + v.z * v.z + v.w * v.w;
#pragma unroll
    for (int off = 1; off < 64; off <<= 1) {
      s += __shfl_xor(s, off);
      q += __shfl_xor(q, off);
    }
    float* ss = &t[0][0];
    float* qq = &t[0][8];
    const int wid = tid >> 6;
    if ((tid & 63) == 0) { ss[wid] = s; qq[wid] = q; }
    __syncthreads();
    s = ss[0] + ss[1] + ss[2] + ss[3];
    q = qq[0] + qq[1] + qq[2] + qq[3];
    const float mean = s * (1.f / DM);
    float var = (q - (float)DM * mean * mean) * (1.f / (DM - 1));
    var = fmaxf(var, 0.f);
    const float inv = 1.f / (sqrtf(var) + 1e-6f);
    const float4 a4 = ((const float4*)alpha)[tid];
    const float4 b4 = ((const float4*)beta)[tid];
    ushort4 o;
    o.x = f2b((v.x - mean) * inv * a4.x + b4.x);
    o.y = f2b((v.y - mean) * inv * a4.y + b4.y);
    o.z = f2b((v.z - mean) * inv * a4.z + b4.z);
    o.w = f2b((v.w - mean) * inv * a4.w + b4.w);
    ((ushort4*)(xout + (size_t)row * DM))[tid] = o;
  }
}

// ---------------- LayerNorm (standalone, for LN2) ----------------
__global__ __launch_bounds__(256)
void ln_kernel(const float* __restrict__ x, const float* __restrict__ alpha,
               const float* __restrict__ beta, u16* __restrict__ out) {
  const int row = blockIdx.x;
  const float4 v = ((const float4*)(x + (size_t)row * DM))[threadIdx.x];
  float s = v.x + v.y + v.z + v.w;
  float q = v.x * v.x + v.y * v.y + v.z * v.z + v.w * v.w;
#pragma unroll
  for (int off = 1; off < 64; off <<= 1) {
    s += __shfl_xor(s, off);
    q += __shfl_xor(q, off);
  }
  __shared__ float ss[4], qq[4];
  const int wid = threadIdx.x >> 6;
  if ((threadIdx.x & 63) == 0) { ss[wid] = s; qq[wid] = q; }
  __syncthreads();
  s = ss[0] + ss[1] + ss[2] + ss[3];
  q = qq[0] + qq[1] + qq[2] + qq[3];
  const float mean = s * (1.f / DM);
  float var = (q - (float)DM * mean * mean) * (1.f / (DM - 1));
  var = fmaxf(var, 0.f);
  const float inv = 1.f / (sqrtf(var) + 1e-6f);
  const float4 a4 = ((const float4*)alpha)[threadIdx.x];
  const float4 b4 = ((const float4*)beta)[threadIdx.x];
  ushort4 o;
  o.x = f2b((v.x - mean) * inv * a4.x + b4.x);
  o.y = f2b((v.y - mean) * inv * a4.y + b4.y);
  o.z = f2b((v.z - mean) * inv * a4.z + b4.z);
  o.w = f2b((v.w - mean) * inv * a4.w + b4.w);
  ((ushort4*)(out + (size_t)row * DM))[threadIdx.x] = o;
}

// ---------------- fused QKV GEMM: QK blocks (mode 0) + V blocks (mode 1) ----------------
__global__ __launch_bounds__(256, 4)
void qkv_gemm(const u16* __restrict__ x2, const u16* __restrict__ Wqkt,
              const u16* __restrict__ Wvt,
              u16* __restrict__ qkb, u16* __restrict__ vtb, float oscale) {
  constexpr int BM = 64, BN = 128, AccM = 2, AccN = 4;
  __shared__ alignas(16) u16 As[3][BM * 32];
  __shared__ alignas(16) u16 Bs[3][BN * 32];
  const int bid = blockIdx.x;
  const int K = DM;
  const u16* A;
  const u16* Bt;
  int bm, bn, mode;
  if (bid < 1024) {
    mode = 0; A = x2; Bt = Wqkt;
    bm = (bid & 63) * BM; bn = (bid >> 6) * BN;
  } else {
    mode = 1; A = Wvt; Bt = x2;
    const int lb = bid - 1024;
    bm = (lb & 15) * BM; bn = (lb >> 4) * BN;
  }
  const int tid = threadIdx.x;
  const int lane = tid & 63, w = tid >> 6;
  const int wm = (w >> 1) * (BM / 2), wn = (w & 1) * (BN / 2);
  const int r = lane & 15, g = lane >> 4;
  const int srow = tid >> 2, skk = (tid & 3) * 8;

  f32x4 acc[AccM][AccN];
#pragma unroll
  for (int i = 0; i < AccM; i++)
#pragma unroll
    for (int j = 0; j < AccN; j++) acc[i][j] = (f32x4){0.f, 0.f, 0.f, 0.f};

  const u16* aP = A + (size_t)(bm + srow) * K + skk;
  const u16* bP = Bt + (size_t)(bn + srow) * K + skk;

  auto stage = [&](int kt, int buf) {
    gload_lds16(aP + kt, &As[buf][0] + w * 512);
    gload_lds16(bP + kt, &Bs[buf][0] + w * 512);
    gload_lds16(bP + (size_t)64 * K + kt, &Bs[buf][0] + w * 512 + 2048);
  };
  auto waitL = [&]() { asm volatile("s_waitcnt vmcnt(3) lgkmcnt(0)" ::: "memory"); };
  auto compute = [&](int buf) {
    bf16x8 af[AccM], bfr[AccN];
#pragma unroll
    for (int i = 0; i < AccM; i++) af[i] = *(const bf16x8*)(&As[buf][(wm + i * 16 + r) * 32 + g * 8]);
#pragma unroll
    for (int j = 0; j < AccN; j++) bfr[j] = *(const bf16x8*)(&Bs[buf][(wn + j * 16 + r) * 32 + g * 8]);
#pragma unroll
    for (int i = 0; i < AccM; i++)
#pragma unroll
      for (int j = 0; j < AccN; j++) acc[i][j] = MFMA16(af[i], bfr[j], acc[i][j]);
  };

  const int NKT = K / 32;
  stage(0, 0);
  stage(32, 1);
  waitL();
  __builtin_amdgcn_s_barrier();
  __builtin_amdgcn_sched_barrier(0);
  for (int it = 0; it < NKT - 2; ++it) {
    stage((it + 2) * 32, (it + 2) % 3);
    compute(it % 3);
    waitL();
    __builtin_amdgcn_s_barrier();
    __builtin_amdgcn_sched_barrier(0);
  }
  compute((NKT - 2) % 3);
  asm volatile("s_waitcnt vmcnt(0) lgkmcnt(0)" ::: "memory");
  __builtin_amdgcn_s_barrier();
  __builtin_amdgcn_sched_barrier(0);
  compute((NKT - 1) % 3);

#pragma unroll
  for (int i = 0; i < AccM; i++)
#pragma unroll
    for (int j = 0; j < AccN; j++)
#pragma unroll
      for (int t = 0; t < 4; t++) {
        const int mg = bm + wm + i * 16 + g * 4 + t;
        const int ng = bn + wn + j * 16 + r;
        const float v = acc[i][j][t];
        if (mode == 0) {
          const int which = ng >> 10, col = ng & 1023;
          const int bb = mg >> 11, ssx = mg & 2047, hh = col >> 6, dd = col & 63;
          const float sc = which ? 1.f : oscale;
          qkb[(size_t)which * (TOK * (size_t)DM) +
              ((size_t)(bb * NH + hh) * SEQ + ssx) * DKK + dd] = f2b(v * sc);
        } else {
          const int hh = mg >> 6, dd = mg & 63, bb = ng >> 11, ssx = ng & 2047;
          vtb[((size_t)(bb * NH + hh) * DKK + dd) * SEQ + ssx] = f2b(v);
        }
      }
}

// ---------------- GEMM (r6 config): triple-buffered LDS, counted vmcnt ----------------
template <int MODE, int BM, int BN>
__global__ __launch_bounds__(256, 4)
void gemm_bt(const u16* __restrict__ A, const u16* __restrict__ Bt,
             int M, int N, int K,
             const float* __restrict__ bias, const float* __restrict__ res,
             void* __restrict__ outp) {
  constexpr int AccM = BM / 32;
  constexpr int AccN = BN / 32;
  constexpr int L = (BM == 128 ? 2 : 1) + (BN == 128 ? 2 : 1);
  __shared__ alignas(16) u16 As[3][BM * 32];
  __shared__ alignas(16) u16 Bs[3][BN * 32];
  const int bm = blockIdx.x * BM, bn = blockIdx.y * BN;
  const int tid = threadIdx.x;
  const int lane = tid & 63, w = tid >> 6;
  const int wm = (w >> 1) * (BM / 2), wn = (w & 1) * (BN / 2);
  const int r = lane & 15, g = lane >> 4;
  const int srow = tid >> 2, skk = (tid & 3) * 8;

  f32x4 acc[AccM][AccN];
#pragma unroll
  for (int i = 0; i < AccM; i++)
#pragma unroll
    for (int j = 0; j < AccN; j++) acc[i][j] = (f32x4){0.f, 0.f, 0.f, 0.f};

  const u16* aP = A + (size_t)(bm + srow) * K + skk;
  const u16* bP = Bt + (size_t)(bn + srow) * K + skk;

  auto stage = [&](int kt, int buf) {
    gload_lds16(aP + kt, &As[buf][0] + w * 512);
    if (BM == 128) gload_lds16(aP + (size_t)64 * K + kt, &As[buf][0] + w * 512 + 2048);
    gload_lds16(bP + kt, &Bs[buf][0] + w * 512);
    if (BN == 128) gload_lds16(bP + (size_t)64 * K + kt, &Bs[buf][0] + w * 512 + 2048);
  };
  auto waitL = [&]() {
    if constexpr (L == 4) asm volatile("s_waitcnt vmcnt(4) lgkmcnt(0)" ::: "memory");
    else if constexpr (L == 3) asm volatile("s_waitcnt vmcnt(3) lgkmcnt(0)" ::: "memory");
    else asm volatile("s_waitcnt vmcnt(2) lgkmcnt(0)" ::: "memory");
  };
  auto compute = [&](int buf) {
    bf16x8 af[AccM], bfr[AccN];
#pragma unroll
    for (int i = 0; i < AccM; i++) af[i] = *(const bf16x8*)(&As[buf][(wm + i * 16 + r) * 32 + g * 8]);
#pragma unroll
    for (int j = 0; j < AccN; j++) bfr[j] = *(const bf16x8*)(&Bs[buf][(wn + j * 16 + r) * 32 + g * 8]);
#pragma unroll
    for (int i = 0; i < AccM; i++)
#pragma unroll
      for (int j = 0; j < AccN; j++) acc[i][j] = MFMA16(af[i], bfr[j], acc[i][j]);
  };

  const int NKT = K / 32;
  stage(0, 0);
  stage(32, 1);
  waitL();
  __builtin_amdgcn_s_barrier();
  __builtin_amdgcn_sched_barrier(0);
  for (int it = 0; it < NKT - 2; ++it) {
    stage((it + 2) * 32, (it + 2) % 3);
    compute(it % 3);
    waitL();
    __builtin_amdgcn_s_barrier();
    __builtin_amdgcn_sched_barrier(0);
  }
  compute((NKT - 2) % 3);
  asm volatile("s_waitcnt vmcnt(0) lgkmcnt(0)" ::: "memory");
  __builtin_amdgcn_s_barrier();
  __builtin_amdgcn_sched_barrier(0);
  compute((NKT - 1) % 3);

#pragma unroll
  for (int i = 0; i < AccM; i++)
#pragma unroll
    for (int j = 0; j < AccN; j++)
#pragma unroll
      for (int t = 0; t < 4; t++) {
        const int mg = bm + wm + i * 16 + g * 4 + t;
        const int ng = bn + wn + j * 16 + r;
        const float v = acc[i][j][t];
        if (MODE == 2) {
          ((float*)outp)[(size_t)mg * N + ng] = res[(size_t)mg * N + ng] + v + bias[ng];
        } else {
          const float hv = v + bias[ng];
          ((u16*)outp)[(size_t)mg * N + ng] = f2b(hv > 0.f ? hv : 0.f);
        }
      }
}

// ---------------- flash attention v11: T15 double-pipeline ----------------
// QK(t) MFMAs issue before softmax+PV(t-1); scores carried in regs.
// K double-buffered (gload_lds), V triple-buffered (rotating pointers).
__global__ __launch_bounds__(256, 4)
void attn_kernel(const u16* __restrict__ Q, const u16* __restrict__ Kb,
                 const u16* __restrict__ Vt, const float* __restrict__ mask,
                 u16* __restrict__ outc) {
  const int bid = blockIdx.x;
  const int bh = (bid & 7) * 4 + ((bid >> 3) & 3);  // 4 heads per XCD
  const int qt = bid >> 5;
  const int b = bh >> 4, h = bh & 15;
  const int tid = threadIdx.x, lane = tid & 63, w = tid >> 6;
  const int r = lane & 15, g = lane >> 4;
  const int qbase = qt * 64 + w * 16;
  const u16* Qp = Q + ((size_t)bh * SEQ + qbase) * DKK;
  const u16* Kp = Kb + (size_t)bh * SEQ * DKK;
  const u16* Vp = Vt + (size_t)bh * DKK * SEQ;
  const float* mk = mask + b * SEQ;

  const bf16x8 bq0 = *(const bf16x8*)(Qp + r * DKK + g * 8);
  const bf16x8 bq1 = *(const bf16x8*)(Qp + r * DKK + 32 + g * 8);

  __shared__ __align__(16) u16 Ks[2][64 * 64];  // 16KB
  __shared__ __align__(16) u16 Vs[3][64 * 64];  // 24KB

  const int srow8 = lane >> 3;
  const int sgr = (lane & 7) ^ srow8;
  const u16* kSrc1 = Kp + (size_t)(w * 16 + srow8) * DKK + sgr * 8;
  const u16* kSrc2 = kSrc1 + 8 * DKK;
  const u16* vSrc1 = Vp + (size_t)(w * 16 + srow8) * SEQ + sgr * 8;
  const u16* vSrc2 = vSrc1 + 8 * SEQ;

  f32x4 o[4];
#pragma unroll
  for (int i = 0; i < 4; i++) o[i] = (f32x4){0.f, 0.f, 0.f, 0.f};
  float lr = 0.f;
  const int keyr = r & 7;

  u16* kCur = &Ks[0][0];
  u16* kNxt = &Ks[1][0];
  u16* vComp = &Vs[2][0];   // V(t-1) during step t
  u16* vReady = &Vs[0][0];  // V(t)
  u16* vStage = &Vs[1][0];  // V(t+1) destination

  // prologue: K(0)->kCur, V(0)->vReady
  gload_lds16(kSrc1, kCur + w * 1024);
  gload_lds16(kSrc2, kCur + w * 1024 + 512);
  gload_lds16(vSrc1, vReady + w * 1024);
  gload_lds16(vSrc2, vReady + w * 1024 + 512);
  asm volatile("s_waitcnt vmcnt(0)" ::: "memory");
  __builtin_amdgcn_s_barrier();
  __builtin_amdgcn_sched_barrier(0);

  f32x4 s[4];
#pragma unroll
  for (int i = 0; i < 4; i++) s[i] = (f32x4){0.f, 0.f, 0.f, 0.f};

  const int NT = SEQ / 64;
  for (int t = 0; t < NT; ++t) {
    // a) stage K(t+1)/V(t+1)
    if (t + 1 < NT) {
      const int nsk = (t + 1) * 64;
      gload_lds16(kSrc1 + (size_t)nsk * DKK, kNxt + w * 1024);
      gload_lds16(kSrc2 + (size_t)nsk * DKK, kNxt + w * 1024 + 512);
      gload_lds16(vSrc1 + nsk, vStage + w * 1024);
      gload_lds16(vSrc2 + nsk, vStage + w * 1024 + 512);
    }
    // b) QK(t) -> sn (not consumed until next step)
    f32x4 sn[4];
    __builtin_amdgcn_s_setprio(1);
#pragma unroll
    for (int ks = 0; ks < 4; ks++) {
      const bf16x8 ka0 = *(const bf16x8*)(kCur + (ks * 16 + r) * 64 + ((g ^ keyr) << 3));
      const bf16x8 ka1 = *(const bf16x8*)(kCur + (ks * 16 + r) * 64 + (((g + 4) ^ keyr) << 3));
      f32x4 z = (f32x4){0.f, 0.f, 0.f, 0.f};
      z = MFMA16(ka0, bq0, z);
      z = MFMA16(ka1, bq1, z);
      sn[ks] = z;
    }
    __builtin_amdgcn_s_setprio(0);
    // c) softmax + PV for tile t-1 (overlaps with b's MFMAs in flight)
    if (t > 0) {
      const int skp = (t - 1) * 64;
      float4 mmv[4];
#pragma unroll
      for (int ks = 0; ks < 4; ks++) mmv[ks] = *(const float4*)(mk + skp + ks * 16 + 4 * g);
      int ones = 1;
#pragma unroll
      for (int ks = 0; ks < 4; ks++)
        ones &= (mmv[ks].x == 1.f) & (mmv[ks].y == 1.f) & (mmv[ks].z == 1.f) & (mmv[ks].w == 1.f);
      const bool fastm = __all(ones);
      float p[16];
      float rs = 0.f;
      if (fastm) {
#pragma unroll
        for (int ks = 0; ks < 4; ks++) {
          float e0 = __builtin_amdgcn_exp2f(s[ks][0]);
          float e1 = __builtin_amdgcn_exp2f(s[ks][1]);
          float e2 = __builtin_amdgcn_exp2f(s[ks][2]);
          float e3 = __builtin_amdgcn_exp2f(s[ks][3]);
          p[ks * 4 + 0] = e0; p[ks * 4 + 1] = e1;
          p[ks * 4 + 2] = e2; p[ks * 4 + 3] = e3;
          rs += e0 + e1 + e2 + e3;
        }
      } else {
#pragma unroll
        for (int ks = 0; ks < 4; ks++) {
          float pr0 = s[ks][0] * mmv[ks].x, pr1 = s[ks][1] * mmv[ks].y;
          float pr2 = s[ks][2] * mmv[ks].z, pr3 = s[ks][3] * mmv[ks].w;
          float e0 = (pr0 == 0.f) ? 0.f : __builtin_amdgcn_exp2f(pr0);
          float e1 = (pr1 == 0.f) ? 0.f : __builtin_amdgcn_exp2f(pr1);
          float e2 = (pr2 == 0.f) ? 0.f : __builtin_amdgcn_exp2f(pr2);
          float e3 = (pr3 == 0.f) ? 0.f : __builtin_amdgcn_exp2f(pr3);
          p[ks * 4 + 0] = e0; p[ks * 4 + 1] = e1;
          p[ks * 4 + 2] = e2; p[ks * 4 + 3] = e3;
          rs += e0 + e1 + e2 + e3;
        }
      }
      rs += __shfl_xor(rs, 16);
      rs += __shfl_xor(rs, 32);
      lr += rs;
      unsigned wk[4][2];
#pragma unroll
      for (int ks = 0; ks < 4; ks++) {
        wk[ks][0] = cvtpk(p[ks * 4 + 0], p[ks * 4 + 1]);
        wk[ks][1] = cvtpk(p[ks * 4 + 2], p[ks * 4 + 3]);
      }
      bf16x8 pa[2];
#pragma unroll
      for (int hh2 = 0; hh2 < 2; hh2++) {
        union { unsigned u[4]; bf16x8 v; } pu;
#pragma unroll
        for (int c = 0; c < 4; c++) {
          const int srcl = r + ((g & 1) * 2 + (c >> 1)) * 16;
          const unsigned lo = __shfl(wk[2 * hh2][c & 1], srcl);
          const unsigned hi = __shfl(wk[2 * hh2 + 1][c & 1], srcl);
          pu.u[c] = (g < 2) ? lo : hi;
        }
        pa[hh2] = pu.v;
      }
      __builtin_amdgcn_s_setprio(1);
#pragma unroll
      for (int dc = 0; dc < 4; dc++) {
        const int vr = dc * 16 + r;
        const bf16x8 bv0 = *(const bf16x8*)(vComp + vr * 64 + ((g ^ keyr) << 3));
        const bf16x8 bv1 = *(const bf16x8*)(vComp + vr * 64 + (((g + 4) ^ keyr) << 3));
        o[dc] = MFMA16(pa[0], bv0, o[dc]);
        o[dc] = MFMA16(pa[1], bv1, o[dc]);
      }
      __builtin_amdgcn_s_setprio(0);
    }
    // d) carry scores; rotate buffers
#pragma unroll
    for (int i = 0; i < 4; i++) s[i] = sn[i];
    u16* tv = vComp; vComp = vReady; vReady = vStage; vStage = tv;
    u16* tk = kCur; kCur = kNxt; kNxt = tk;
    // e) end-of-step sync (prefetches issued in (a) had the whole step to land)
    asm volatile("s_waitcnt vmcnt(0) lgkmcnt(0)" ::: "memory");
    __builtin_amdgcn_s_barrier();
    __builtin_amdgcn_sched_barrier(0);
  }

  // tail: softmax + PV for tile NT-1 (vComp == V(NT-1) after final rotation)
  {
    const int skp = (NT - 1) * 64;
    float4 mmv[4];
#pragma unroll
    for (int ks = 0; ks < 4; ks++) mmv[ks] = *(const float4*)(mk + skp + ks * 16 + 4 * g);
    int ones = 1;
#pragma unroll
    for (int ks = 0; ks < 4; ks++)
      ones &= (mmv[ks].x == 1.f) & (mmv[ks].y == 1.f) & (mmv[ks].z == 1.f) & (mmv[ks].w == 1.f);
    const bool fastm = __all(ones);
    float p[16];
    float rs = 0.f;
    if (fastm) {
#pragma unroll
      for (int ks = 0; ks < 4; ks++) {
        float e0 = __builtin_amdgcn_exp2f(s[ks][0]);
        float e1 = __builtin_amdgcn_exp2f(s[ks][1]);
        float e2 = __builtin_amdgcn_exp2f(s[ks][2]);
        float e3 = __builtin_amdgcn_exp2f(s[ks][3]);
        p[ks * 4 + 0] = e0; p[ks * 4 + 1] = e1;
        p[ks * 4 + 2] = e2; p[ks * 4 + 3] = e3;
        rs += e0 + e1 + e2 + e3;
      }
    } else {
#pragma unroll
      for (int ks = 0; ks < 4; ks++) {
        float pr0 = s[ks][0] * mmv[ks].x, pr1 = s[ks][1] * mmv[ks].y;
        float pr2 = s[ks][2] * mmv[ks].z, pr3 = s[ks][3] * mmv[ks].w;
        float e0 = (pr0 == 0.f) ? 0.f : __builtin_amdgcn_exp2f(pr0);
        float e1 = (pr1 == 0.f) ? 0.f : __builtin_amdgcn_exp2f(pr1);
        float e2 = (pr2 == 0.f) ? 0.f : __builtin_amdgcn_exp2f(pr2);
        float e3 = (pr3 == 0.f) ? 0.f : __builtin_amdgcn_exp2f(pr3);
        p[ks * 4 + 0] = e0; p[ks * 4 + 1] = e1;
        p[ks * 4 + 2] = e2; p[ks * 4 + 3] = e3;
        rs += e0 + e1 + e2 + e3;
      }
    }
    rs += __shfl_xor(rs, 16);
    rs += __shfl_xor(rs, 32);
    lr += rs;
    unsigned wk[4][2];
#pragma unroll
    for (int ks = 0; ks < 4; ks++) {
      wk[ks][0] = cvtpk(p[ks * 4 + 0], p[ks * 4 + 1]);
      wk[ks][1] = cvtpk(p[ks * 4 + 2], p[ks * 4 + 3]);
    }
    bf16x8 pa[2];
#pragma unroll
    for (int hh2 = 0; hh2 < 2; hh2++) {
      union { unsigned u[4]; bf16x8 v; } pu;
#pragma unroll
      for (int c = 0; c < 4; c++) {
        const int srcl = r + ((g & 1) * 2 + (c >> 1)) * 16;
        const unsigned lo = __shfl(wk[2 * hh2][c & 1], srcl);
        const unsigned hi = __shfl(wk[2 * hh2 + 1][c & 1], srcl);
        pu.u[c] = (g < 2) ? lo : hi;
      }
      pa[hh2] = pu.v;
    }
#pragma unroll
    for (int dc = 0; dc < 4; dc++) {
      const int vr = dc * 16 + r;
      const bf16x8 bv0 = *(const bf16x8*)(vComp + vr * 64 + ((g ^ keyr) << 3));
      const bf16x8 bv1 = *(const bf16x8*)(vComp + vr * 64 + (((g + 4) ^ keyr) << 3));
      o[dc] = MFMA16(pa[0], bv0, o[dc]);
      o[dc] = MFMA16(pa[1], bv1, o[dc]);
    }
  }

  float lq[4];
#pragma unroll
  for (int t = 0; t < 4; t++) lq[t] = __shfl(lr, 4 * g + t);
#pragma unroll
  for (int dc = 0; dc < 4; dc++)
#pragma unroll
    for (int t = 0; t < 4; t++) {
      const int srow_g = qbase + g * 4 + t;
      outc[((size_t)(b * SEQ + srow_g)) * DM + h * DKK + dc * 16 + r] = f2b(o[dc][t] / lq[t]);
    }
}

extern "C" void kernel_launch(void* const* d_in, const int* in_sizes, int n_in,
                              void* d_out, int out_size, void* d_ws, size_t ws_size,
                              hipStream_t stream) {
  const float* x    = (const float*)d_in[0];
  const float* mask = (const float*)d_in[1];
  const float* Wq   = (const float*)d_in[2];
  const float* Wk   = (const float*)d_in[3];
  const float* Wv   = (const float*)d_in[4];
  const float* Wo   = (const float*)d_in[5];
  const float* bo   = (const float*)d_in[6];
  const float* W1   = (const float*)d_in[7];
  const float* b1   = (const float*)d_in[8];
  const float* W2   = (const float*)d_in[9];
  const float* b2   = (const float*)d_in[10];
  const float* l1a  = (const float*)d_in[11];
  const float* l1b  = (const float*)d_in[12];
  const float* l2a  = (const float*)d_in[13];
  const float* l2b  = (const float*)d_in[14];

  char* wsb = (char*)d_ws;
  u16* Wqkt = (u16*)(wsb + (0ull << 20));
  u16* Wvt  = (u16*)(wsb + (4ull << 20));
  u16* Wot  = (u16*)(wsb + (6ull << 20));
  u16* W1t  = (u16*)(wsb + (8ull << 20));
  u16* W2t  = (u16*)(wsb + (12ull << 20));
  u16* x2   = (u16*)(wsb + (16ull << 20));
  u16* qkb  = (u16*)(wsb + (24ull << 20));
  u16* vtb  = (u16*)(wsb + (40ull << 20));
  float* x1 = (float*)(wsb + (48ull << 20));
  u16* concat = x2;
  u16* x2b = qkb;
  u16* hb  = (u16*)(wsb + (32ull << 20));

  const float qscale = 0.125f * 1.4426950408889634f;

  prep_all<<<dim3(12288), 256, 0, stream>>>(Wq, Wk, Wv, Wo, W1, W2,
                                            Wqkt, Wvt, Wot, W1t, W2t,
                                            x, l1a, l1b, x2);

  qkv_gemm<<<dim3(1536), 256, 0, stream>>>(x2, Wqkt, Wvt, qkb, vtb, qscale);

  attn_kernel<<<dim3(1024), 256, 0, stream>>>(qkb, qkb + (size_t)TOK * DM, vtb, mask, concat);

  gemm_bt<2, 64, 64><<<dim3(TOK / 64, DM / 64), 256, 0, stream>>>(
      concat, Wot, TOK, DM, DM, bo, x, x1);

  ln_kernel<<<TOK, 256, 0, stream>>>(x1, l2a, l2b, x2b);

  gemm_bt<3, 64, 128><<<dim3(TOK / 64, DFF / 128), 256, 0, stream>>>(
      x2b, W1t, TOK, DFF, DM, b1, nullptr, hb);
  gemm_bt<2, 64, 64><<<dim3(TOK / 64, DM / 64), 256, 0, stream>>>(
      hb, W2t, TOK, DM, DFF, b2, x1, (float*)d_out);
}

// Round 12
// 213.186 us; speedup vs baseline: 1.0367x; 1.0367x over previous
//
#include <hip/hip_runtime.h>
#include <hip/hip_bf16.h>

typedef unsigned short u16;
typedef __attribute__((ext_vector_type(4))) float f32x4;
typedef __attribute__((ext_vector_type(8))) short bf16x8;

#define SEQ 2048
#define DM 1024
#define DKK 64
#define NH 16
#define DFF 2048
#define TOK 4096

#define AS1 __attribute__((address_space(1)))
#define AS3 __attribute__((address_space(3)))

#define MFMA16(a, b, c) __builtin_amdgcn_mfma_f32_16x16x32_bf16((a), (b), (c), 0, 0, 0)

__device__ __forceinline__ u16 f2b(float f) {
  unsigned u = __float_as_uint(f);
  u = u + 0x7fffu + ((u >> 16) & 1u);
  return (u16)(u >> 16);
}

__device__ __forceinline__ unsigned cvtpk(float lo, float hi) {
  unsigned r;
  asm("v_cvt_pk_bf16_f32 %0, %1, %2" : "=v"(r) : "v"(lo), "v"(hi));
  return r;
}

__device__ __forceinline__ void gload_lds16(const u16* g, u16* l) {
  __builtin_amdgcn_global_load_lds((AS1 unsigned*)(size_t)g, (AS3 unsigned*)l, 16, 0, 0);
}

// ------- fused prep: 6 weight transposes (fp32 [K,N] -> bf16 [N,K]) + LayerNorm1 -------
__global__ __launch_bounds__(256)
void prep_all(const float* __restrict__ Wq, const float* __restrict__ Wk,
              const float* __restrict__ Wv, const float* __restrict__ Wo,
              const float* __restrict__ W1, const float* __restrict__ W2,
              u16* __restrict__ Wqkt, u16* __restrict__ Wvt, u16* __restrict__ Wot,
              u16* __restrict__ W1t, u16* __restrict__ W2t,
              const float* __restrict__ x, const float* __restrict__ alpha,
              const float* __restrict__ beta, u16* __restrict__ xout) {
  __shared__ float t[32][33];
  const int bid = blockIdx.x;
  const int tid = threadIdx.x;
  if (bid < 8192) {  // transpose path
    const float* src;
    u16* dst;
    int K, N, lb;
    if (bid < 1024)      { src = Wq; dst = Wqkt;             K = 1024; N = 1024; lb = bid; }
    else if (bid < 2048) { src = Wk; dst = Wqkt + (1 << 20); K = 1024; N = 1024; lb = bid - 1024; }
    else if (bid < 3072) { src = Wv; dst = Wvt;              K = 1024; N = 1024; lb = bid - 2048; }
    else if (bid < 4096) { src = Wo; dst = Wot;              K = 1024; N = 1024; lb = bid - 3072; }
    else if (bid < 6144) { src = W1; dst = W1t;              K = 1024; N = 2048; lb = bid - 4096; }
    else                 { src = W2; dst = W2t;              K = 2048; N = 1024; lb = bid - 6144; }
    const int nx = N / 32;
    const int n0 = (lb % nx) * 32, k0 = (lb / nx) * 32;
    const int tx = tid & 31, ty = tid >> 5;
#pragma unroll
    for (int i = 0; i < 4; i++) {
      int k = ty + i * 8;
      t[k][tx] = src[(size_t)(k0 + k) * N + n0 + tx];
    }
    __syncthreads();
#pragma unroll
    for (int i = 0; i < 4; i++) {
      int n = ty + i * 8;
      dst[(size_t)(n0 + n) * K + k0 + tx] = f2b(t[tx][n]);
    }
  } else {  // LayerNorm1 path
    const int row = bid - 8192;
    const float4 v = ((const float4*)(x + (size_t)row * DM))[tid];
    float s = v.x + v.y + v.z + v.w;
    float q = v.x * v.x + v.y * v.y + v.z * v.z + v.w * v.w;
#pragma unroll
    for (int off = 1; off < 64; off <<= 1) {
      s += __shfl_xor(s, off);
      q += __shfl_xor(q, off);
    }
    float* ss = &t[0][0];
    float* qq = &t[0][8];
    const int wid = tid >> 6;
    if ((tid & 63) == 0) { ss[wid] = s; qq[wid] = q; }
    __syncthreads();
    s = ss[0] + ss[1] + ss[2] + ss[3];
    q = qq[0] + qq[1] + qq[2] + qq[3];
    const float mean = s * (1.f / DM);
    float var = (q - (float)DM * mean * mean) * (1.f / (DM - 1));
    var = fmaxf(var, 0.f);
    const float inv = 1.f / (sqrtf(var) + 1e-6f);
    const float4 a4 = ((const float4*)alpha)[tid];
    const float4 b4 = ((const float4*)beta)[tid];
    ushort4 o;
    o.x = f2b((v.x - mean) * inv * a4.x + b4.x);
    o.y = f2b((v.y - mean) * inv * a4.y + b4.y);
    o.z = f2b((v.z - mean) * inv * a4.z + b4.z);
    o.w = f2b((v.w - mean) * inv * a4.w + b4.w);
    ((ushort4*)(xout + (size_t)row * DM))[tid] = o;
  }
}

// ---------------- LayerNorm (standalone, for LN2) ----------------
__global__ __launch_bounds__(256)
void ln_kernel(const float* __restrict__ x, const float* __restrict__ alpha,
               const float* __restrict__ beta, u16* __restrict__ out) {
  const int row = blockIdx.x;
  const float4 v = ((const float4*)(x + (size_t)row * DM))[threadIdx.x];
  float s = v.x + v.y + v.z + v.w;
  float q = v.x * v.x + v.y * v.y + v.z * v.z + v.w * v.w;
#pragma unroll
  for (int off = 1; off < 64; off <<= 1) {
    s += __shfl_xor(s, off);
    q += __shfl_xor(q, off);
  }
  __shared__ float ss[4], qq[4];
  const int wid = threadIdx.x >> 6;
  if ((threadIdx.x & 63) == 0) { ss[wid] = s; qq[wid] = q; }
  __syncthreads();
  s = ss[0] + ss[1] + ss[2] + ss[3];
  q = qq[0] + qq[1] + qq[2] + qq[3];
  const float mean = s * (1.f / DM);
  float var = (q - (float)DM * mean * mean) * (1.f / (DM - 1));
  var = fmaxf(var, 0.f);
  const float inv = 1.f / (sqrtf(var) + 1e-6f);
  const float4 a4 = ((const float4*)alpha)[threadIdx.x];
  const float4 b4 = ((const float4*)beta)[threadIdx.x];
  ushort4 o;
  o.x = f2b((v.x - mean) * inv * a4.x + b4.x);
  o.y = f2b((v.y - mean) * inv * a4.y + b4.y);
  o.z = f2b((v.z - mean) * inv * a4.z + b4.z);
  o.w = f2b((v.w - mean) * inv * a4.w + b4.w);
  ((ushort4*)(out + (size_t)row * DM))[threadIdx.x] = o;
}

// ---------------- fused QKV GEMM: QK blocks (mode 0) + V blocks (mode 1) ----------------
__global__ __launch_bounds__(256, 4)
void qkv_gemm(const u16* __restrict__ x2, const u16* __restrict__ Wqkt,
              const u16* __restrict__ Wvt,
              u16* __restrict__ qkb, u16* __restrict__ vtb, float oscale) {
  constexpr int BM = 64, BN = 128, AccM = 2, AccN = 4;
  __shared__ alignas(16) u16 As[3][BM * 32];
  __shared__ alignas(16) u16 Bs[3][BN * 32];
  const int bid = blockIdx.x;
  const int K = DM;
  const u16* A;
  const u16* Bt;
  int bm, bn, mode;
  if (bid < 1024) {
    mode = 0; A = x2; Bt = Wqkt;
    bm = (bid & 63) * BM; bn = (bid >> 6) * BN;
  } else {
    mode = 1; A = Wvt; Bt = x2;
    const int lb = bid - 1024;
    bm = (lb & 15) * BM; bn = (lb >> 4) * BN;
  }
  const int tid = threadIdx.x;
  const int lane = tid & 63, w = tid >> 6;
  const int wm = (w >> 1) * (BM / 2), wn = (w & 1) * (BN / 2);
  const int r = lane & 15, g = lane >> 4;
  const int srow = tid >> 2, skk = (tid & 3) * 8;

  f32x4 acc[AccM][AccN];
#pragma unroll
  for (int i = 0; i < AccM; i++)
#pragma unroll
    for (int j = 0; j < AccN; j++) acc[i][j] = (f32x4){0.f, 0.f, 0.f, 0.f};

  const u16* aP = A + (size_t)(bm + srow) * K + skk;
  const u16* bP = Bt + (size_t)(bn + srow) * K + skk;

  auto stage = [&](int kt, int buf) {
    gload_lds16(aP + kt, &As[buf][0] + w * 512);
    gload_lds16(bP + kt, &Bs[buf][0] + w * 512);
    gload_lds16(bP + (size_t)64 * K + kt, &Bs[buf][0] + w * 512 + 2048);
  };
  auto waitL = [&]() { asm volatile("s_waitcnt vmcnt(3) lgkmcnt(0)" ::: "memory"); };
  auto compute = [&](int buf) {
    bf16x8 af[AccM], bfr[AccN];
#pragma unroll
    for (int i = 0; i < AccM; i++) af[i] = *(const bf16x8*)(&As[buf][(wm + i * 16 + r) * 32 + g * 8]);
#pragma unroll
    for (int j = 0; j < AccN; j++) bfr[j] = *(const bf16x8*)(&Bs[buf][(wn + j * 16 + r) * 32 + g * 8]);
#pragma unroll
    for (int i = 0; i < AccM; i++)
#pragma unroll
      for (int j = 0; j < AccN; j++) acc[i][j] = MFMA16(af[i], bfr[j], acc[i][j]);
  };

  const int NKT = K / 32;
  stage(0, 0);
  stage(32, 1);
  waitL();
  __builtin_amdgcn_s_barrier();
  __builtin_amdgcn_sched_barrier(0);
  for (int it = 0; it < NKT - 2; ++it) {
    stage((it + 2) * 32, (it + 2) % 3);
    compute(it % 3);
    waitL();
    __builtin_amdgcn_s_barrier();
    __builtin_amdgcn_sched_barrier(0);
  }
  compute((NKT - 2) % 3);
  asm volatile("s_waitcnt vmcnt(0) lgkmcnt(0)" ::: "memory");
  __builtin_amdgcn_s_barrier();
  __builtin_amdgcn_sched_barrier(0);
  compute((NKT - 1) % 3);

#pragma unroll
  for (int i = 0; i < AccM; i++)
#pragma unroll
    for (int j = 0; j < AccN; j++)
#pragma unroll
      for (int t = 0; t < 4; t++) {
        const int mg = bm + wm + i * 16 + g * 4 + t;
        const int ng = bn + wn + j * 16 + r;
        const float v = acc[i][j][t];
        if (mode == 0) {
          const int which = ng >> 10, col = ng & 1023;
          const int bb = mg >> 11, ssx = mg & 2047, hh = col >> 6, dd = col & 63;
          const float sc = which ? 1.f : oscale;
          qkb[(size_t)which * (TOK * (size_t)DM) +
              ((size_t)(bb * NH + hh) * SEQ + ssx) * DKK + dd] = f2b(v * sc);
        } else {
          const int hh = mg >> 6, dd = mg & 63, bb = ng >> 11, ssx = ng & 2047;
          vtb[((size_t)(bb * NH + hh) * DKK + dd) * SEQ + ssx] = f2b(v);
        }
      }
}

// ---------------- GEMM (r6 config): triple-buffered LDS, counted vmcnt ----------------
template <int MODE, int BM, int BN>
__global__ __launch_bounds__(256, 4)
void gemm_bt(const u16* __restrict__ A, const u16* __restrict__ Bt,
             int M, int N, int K,
             const float* __restrict__ bias, const float* __restrict__ res,
             void* __restrict__ outp) {
  constexpr int AccM = BM / 32;
  constexpr int AccN = BN / 32;
  constexpr int L = (BM == 128 ? 2 : 1) + (BN == 128 ? 2 : 1);
  __shared__ alignas(16) u16 As[3][BM * 32];
  __shared__ alignas(16) u16 Bs[3][BN * 32];
  const int bm = blockIdx.x * BM, bn = blockIdx.y * BN;
  const int tid = threadIdx.x;
  const int lane = tid & 63, w = tid >> 6;
  const int wm = (w >> 1) * (BM / 2), wn = (w & 1) * (BN / 2);
  const int r = lane & 15, g = lane >> 4;
  const int srow = tid >> 2, skk = (tid & 3) * 8;

  f32x4 acc[AccM][AccN];
#pragma unroll
  for (int i = 0; i < AccM; i++)
#pragma unroll
    for (int j = 0; j < AccN; j++) acc[i][j] = (f32x4){0.f, 0.f, 0.f, 0.f};

  const u16* aP = A + (size_t)(bm + srow) * K + skk;
  const u16* bP = Bt + (size_t)(bn + srow) * K + skk;

  auto stage = [&](int kt, int buf) {
    gload_lds16(aP + kt, &As[buf][0] + w * 512);
    if (BM == 128) gload_lds16(aP + (size_t)64 * K + kt, &As[buf][0] + w * 512 + 2048);
    gload_lds16(bP + kt, &Bs[buf][0] + w * 512);
    if (BN == 128) gload_lds16(bP + (size_t)64 * K + kt, &Bs[buf][0] + w * 512 + 2048);
  };
  auto waitL = [&]() {
    if constexpr (L == 4) asm volatile("s_waitcnt vmcnt(4) lgkmcnt(0)" ::: "memory");
    else if constexpr (L == 3) asm volatile("s_waitcnt vmcnt(3) lgkmcnt(0)" ::: "memory");
    else asm volatile("s_waitcnt vmcnt(2) lgkmcnt(0)" ::: "memory");
  };
  auto compute = [&](int buf) {
    bf16x8 af[AccM], bfr[AccN];
#pragma unroll
    for (int i = 0; i < AccM; i++) af[i] = *(const bf16x8*)(&As[buf][(wm + i * 16 + r) * 32 + g * 8]);
#pragma unroll
    for (int j = 0; j < AccN; j++) bfr[j] = *(const bf16x8*)(&Bs[buf][(wn + j * 16 + r) * 32 + g * 8]);
#pragma unroll
    for (int i = 0; i < AccM; i++)
#pragma unroll
      for (int j = 0; j < AccN; j++) acc[i][j] = MFMA16(af[i], bfr[j], acc[i][j]);
  };

  const int NKT = K / 32;
  stage(0, 0);
  stage(32, 1);
  waitL();
  __builtin_amdgcn_s_barrier();
  __builtin_amdgcn_sched_barrier(0);
  for (int it = 0; it < NKT - 2; ++it) {
    stage((it + 2) * 32, (it + 2) % 3);
    compute(it % 3);
    waitL();
    __builtin_amdgcn_s_barrier();
    __builtin_amdgcn_sched_barrier(0);
  }
  compute((NKT - 2) % 3);
  asm volatile("s_waitcnt vmcnt(0) lgkmcnt(0)" ::: "memory");
  __builtin_amdgcn_s_barrier();
  __builtin_amdgcn_sched_barrier(0);
  compute((NKT - 1) % 3);

#pragma unroll
  for (int i = 0; i < AccM; i++)
#pragma unroll
    for (int j = 0; j < AccN; j++)
#pragma unroll
      for (int t = 0; t < 4; t++) {
        const int mg = bm + wm + i * 16 + g * 4 + t;
        const int ng = bn + wn + j * 16 + r;
        const float v = acc[i][j][t];
        if (MODE == 2) {
          ((float*)outp)[(size_t)mg * N + ng] = res[(size_t)mg * N + ng] + v + bias[ng];
        } else {
          const float hv = v + bias[ng];
          ((u16*)outp)[(size_t)mg * N + ng] = f2b(hv > 0.f ? hv : 0.f);
        }
      }
}

// ---------------- flash attention v12: 8 waves / 128 q-rows share one K/V stream ----------
// r10 step body; staging halved per wave (1 K gload + 1 V gload per tile).
__global__ __launch_bounds__(512, 2)
void attn_kernel(const u16* __restrict__ Q, const u16* __restrict__ Kb,
                 const u16* __restrict__ Vt, const float* __restrict__ mask,
                 u16* __restrict__ outc) {
  const int bid = blockIdx.x;
  const int bh = (bid & 7) * 4 + ((bid >> 3) & 3);  // 4 heads per XCD
  const int qt = bid >> 5;                          // 0..15 (128-row q tiles)
  const int b = bh >> 4, h = bh & 15;
  const int tid = threadIdx.x, lane = tid & 63, w = tid >> 6;  // w = 0..7
  const int r = lane & 15, g = lane >> 4;
  const int qbase = qt * 128 + w * 16;
  const u16* Qp = Q + ((size_t)bh * SEQ + qbase) * DKK;
  const u16* Kp = Kb + (size_t)bh * SEQ * DKK;
  const u16* Vp = Vt + (size_t)bh * DKK * SEQ;
  const float* mk = mask + b * SEQ;

  const bf16x8 bq0 = *(const bf16x8*)(Qp + r * DKK + g * 8);
  const bf16x8 bq1 = *(const bf16x8*)(Qp + r * DKK + 32 + g * 8);

  __shared__ __align__(16) u16 Ks[2][64 * 64];
  __shared__ __align__(16) u16 Vs[2][64 * 64];

  // wave w stages rows w*8..w*8+7 of each 64-row tile (1 gload each for K and V)
  const int srow8 = lane >> 3;
  const int sgr = (lane & 7) ^ srow8;  // row key (w*8+srow8)&7 == srow8
  const u16* kSrc = Kp + (size_t)(w * 8 + srow8) * DKK + sgr * 8;
  const u16* vSrc = Vp + (size_t)(w * 8 + srow8) * SEQ + sgr * 8;

  f32x4 o[4];
#pragma unroll
  for (int i = 0; i < 4; i++) o[i] = (f32x4){0.f, 0.f, 0.f, 0.f};
  float lr = 0.f;
  const int keyr = r & 7;

  gload_lds16(kSrc, &Ks[0][0] + w * 512);
  gload_lds16(vSrc, &Vs[0][0] + w * 512);
  asm volatile("s_waitcnt vmcnt(0)" ::: "memory");
  __builtin_amdgcn_s_barrier();
  __builtin_amdgcn_sched_barrier(0);

  const int NT = SEQ / 64;

#define ATTN_STEP(IT, BUF)                                                         \
  do {                                                                             \
    if ((IT) + 1 < NT) {                                                           \
      const int nsk = ((IT) + 1) * 64;                                             \
      gload_lds16(kSrc + (size_t)nsk * DKK, &Ks[(BUF) ^ 1][0] + w * 512);          \
      gload_lds16(vSrc + nsk, &Vs[(BUF) ^ 1][0] + w * 512);                        \
    }                                                                              \
    f32x4 s[4];                                                                    \
    __builtin_amdgcn_s_setprio(1);                                                 \
    _Pragma("unroll")                                                              \
    for (int ks = 0; ks < 4; ks++) {                                               \
      const bf16x8 ka0 = *(const bf16x8*)&Ks[BUF][(ks * 16 + r) * 64 + ((g ^ keyr) << 3)];        \
      const bf16x8 ka1 = *(const bf16x8*)&Ks[BUF][(ks * 16 + r) * 64 + (((g + 4) ^ keyr) << 3)];  \
      f32x4 z = (f32x4){0.f, 0.f, 0.f, 0.f};                                       \
      z = MFMA16(ka0, bq0, z);                                                     \
      z = MFMA16(ka1, bq1, z);                                                     \
      s[ks] = z;                                                                   \
    }                                                                              \
    __builtin_amdgcn_s_setprio(0);                                                 \
    const int sk = (IT) * 64;                                                      \
    float4 mmv[4];                                                                 \
    _Pragma("unroll")                                                              \
    for (int ks = 0; ks < 4; ks++) mmv[ks] = *(const float4*)(mk + sk + ks * 16 + 4 * g); \
    int ones = 1;                                                                  \
    _Pragma("unroll")                                                              \
    for (int ks = 0; ks < 4; ks++)                                                 \
      ones &= (mmv[ks].x == 1.f) & (mmv[ks].y == 1.f) & (mmv[ks].z == 1.f) & (mmv[ks].w == 1.f); \
    const bool fastm = __all(ones);                                                \
    float p[16];                                                                   \
    float rs = 0.f;                                                                \
    if (fastm) {                                                                   \
      _Pragma("unroll")                                                            \
      for (int ks = 0; ks < 4; ks++) {                                             \
        float e0 = __builtin_amdgcn_exp2f(s[ks][0]);                               \
        float e1 = __builtin_amdgcn_exp2f(s[ks][1]);                               \
        float e2 = __builtin_amdgcn_exp2f(s[ks][2]);                               \
        float e3 = __builtin_amdgcn_exp2f(s[ks][3]);                               \
        p[ks * 4 + 0] = e0; p[ks * 4 + 1] = e1;                                    \
        p[ks * 4 + 2] = e2; p[ks * 4 + 3] = e3;                                    \
        rs += e0 + e1 + e2 + e3;                                                   \
      }                                                                            \
    } else {                                                                       \
      _Pragma("unroll")                                                            \
      for (int ks = 0; ks < 4; ks++) {                                             \
        float pr0 = s[ks][0] * mmv[ks].x, pr1 = s[ks][1] * mmv[ks].y;              \
        float pr2 = s[ks][2] * mmv[ks].z, pr3 = s[ks][3] * mmv[ks].w;              \
        float e0 = (pr0 == 0.f) ? 0.f : __builtin_amdgcn_exp2f(pr0);               \
        float e1 = (pr1 == 0.f) ? 0.f : __builtin_amdgcn_exp2f(pr1);               \
        float e2 = (pr2 == 0.f) ? 0.f : __builtin_amdgcn_exp2f(pr2);               \
        float e3 = (pr3 == 0.f) ? 0.f : __builtin_amdgcn_exp2f(pr3);               \
        p[ks * 4 + 0] = e0; p[ks * 4 + 1] = e1;                                    \
        p[ks * 4 + 2] = e2; p[ks * 4 + 3] = e3;                                    \
        rs += e0 + e1 + e2 + e3;                                                   \
      }                                                                            \
    }                                                                              \
    rs += __shfl_xor(rs, 16);                                                      \
    rs += __shfl_xor(rs, 32);                                                      \
    lr += rs;                                                                      \
    unsigned wk[4][2];                                                             \
    _Pragma("unroll")                                                              \
    for (int ks = 0; ks < 4; ks++) {                                               \
      wk[ks][0] = cvtpk(p[ks * 4 + 0], p[ks * 4 + 1]);                             \
      wk[ks][1] = cvtpk(p[ks * 4 + 2], p[ks * 4 + 3]);                             \
    }                                                                              \
    bf16x8 pa[2];                                                                  \
    _Pragma("unroll")                                                              \
    for (int hh2 = 0; hh2 < 2; hh2++) {                                            \
      union { unsigned u[4]; bf16x8 v; } pu;                                       \
      _Pragma("unroll")                                                            \
      for (int c = 0; c < 4; c++) {                                                \
        const int srcl = r + ((g & 1) * 2 + (c >> 1)) * 16;                        \
        const unsigned lo = __shfl(wk[2 * hh2][c & 1], srcl);                      \
        const unsigned hi = __shfl(wk[2 * hh2 + 1][c & 1], srcl);                  \
        pu.u[c] = (g < 2) ? lo : hi;                                               \
      }                                                                            \
      pa[hh2] = pu.v;                                                              \
    }                                                                              \
    __builtin_amdgcn_s_setprio(1);                                                 \
    _Pragma("unroll")                                                              \
    for (int dc = 0; dc < 4; dc++) {                                               \
      const int vr = dc * 16 + r;                                                  \
      const bf16x8 bv0 = *(const bf16x8*)&Vs[BUF][vr * 64 + ((g ^ keyr) << 3)];    \
      const bf16x8 bv1 = *(const bf16x8*)&Vs[BUF][vr * 64 + (((g + 4) ^ keyr) << 3)]; \
      o[dc] = MFMA16(pa[0], bv0, o[dc]);                                           \
      o[dc] = MFMA16(pa[1], bv1, o[dc]);                                           \
    }                                                                              \
    __builtin_amdgcn_s_setprio(0);                                                 \
    asm volatile("s_waitcnt vmcnt(0) lgkmcnt(0)" ::: "memory");                    \
    __builtin_amdgcn_s_barrier();                                                  \
    __builtin_amdgcn_sched_barrier(0);                                             \
  } while (0)

  for (int it = 0; it < NT; it += 2) {
    ATTN_STEP(it, 0);
    ATTN_STEP(it + 1, 1);
  }
#undef ATTN_STEP

  float lq[4];
#pragma unroll
  for (int t = 0; t < 4; t++) lq[t] = __shfl(lr, 4 * g + t);
#pragma unroll
  for (int dc = 0; dc < 4; dc++)
#pragma unroll
    for (int t = 0; t < 4; t++) {
      const int srow_g = qbase + g * 4 + t;
      outc[((size_t)(b * SEQ + srow_g)) * DM + h * DKK + dc * 16 + r] = f2b(o[dc][t] / lq[t]);
    }
}

extern "C" void kernel_launch(void* const* d_in, const int* in_sizes, int n_in,
                              void* d_out, int out_size, void* d_ws, size_t ws_size,
                              hipStream_t stream) {
  const float* x    = (const float*)d_in[0];
  const float* mask = (const float*)d_in[1];
  const float* Wq   = (const float*)d_in[2];
  const float* Wk   = (const float*)d_in[3];
  const float* Wv   = (const float*)d_in[4];
  const float* Wo   = (const float*)d_in[5];
  const float* bo   = (const float*)d_in[6];
  const float* W1   = (const float*)d_in[7];
  const float* b1   = (const float*)d_in[8];
  const float* W2   = (const float*)d_in[9];
  const float* b2   = (const float*)d_in[10];
  const float* l1a  = (const float*)d_in[11];
  const float* l1b  = (const float*)d_in[12];
  const float* l2a  = (const float*)d_in[13];
  const float* l2b  = (const float*)d_in[14];

  char* wsb = (char*)d_ws;
  u16* Wqkt = (u16*)(wsb + (0ull << 20));
  u16* Wvt  = (u16*)(wsb + (4ull << 20));
  u16* Wot  = (u16*)(wsb + (6ull << 20));
  u16* W1t  = (u16*)(wsb + (8ull << 20));
  u16* W2t  = (u16*)(wsb + (12ull << 20));
  u16* x2   = (u16*)(wsb + (16ull << 20));
  u16* qkb  = (u16*)(wsb + (24ull << 20));
  u16* vtb  = (u16*)(wsb + (40ull << 20));
  float* x1 = (float*)(wsb + (48ull << 20));
  u16* concat = x2;
  u16* x2b = qkb;
  u16* hb  = (u16*)(wsb + (32ull << 20));

  const float qscale = 0.125f * 1.4426950408889634f;

  prep_all<<<dim3(12288), 256, 0, stream>>>(Wq, Wk, Wv, Wo, W1, W2,
                                            Wqkt, Wvt, Wot, W1t, W2t,
                                            x, l1a, l1b, x2);

  qkv_gemm<<<dim3(1536), 256, 0, stream>>>(x2, Wqkt, Wvt, qkb, vtb, qscale);

  attn_kernel<<<dim3(512), 512, 0, stream>>>(qkb, qkb + (size_t)TOK * DM, vtb, mask, concat);

  gemm_bt<2, 64, 64><<<dim3(TOK / 64, DM / 64), 256, 0, stream>>>(
      concat, Wot, TOK, DM, DM, bo, x, x1);

  ln_kernel<<<TOK, 256, 0, stream>>>(x1, l2a, l2b, x2b);

  gemm_bt<3, 64, 128><<<dim3(TOK / 64, DFF / 128), 256, 0, stream>>>(
      x2b, W1t, TOK, DFF, DM, b1, nullptr, hb);
  gemm_bt<2, 64, 64><<<dim3(TOK / 64, DM / 64), 256, 0, stream>>>(
      hb, W2t, TOK, DM, DFF, b2, x1, (float*)d_out);
}

// Round 13
// 212.804 us; speedup vs baseline: 1.0385x; 1.0018x over previous
//
#include <hip/hip_runtime.h>
#include <hip/hip_bf16.h>

typedef unsigned short u16;
typedef __attribute__((ext_vector_type(4))) float f32x4;
typedef __attribute__((ext_vector_type(8))) short bf16x8;

#define SEQ 2048
#define DM 1024
#define DKK 64
#define NH 16
#define DFF 2048
#define TOK 4096

#define AS1 __attribute__((address_space(1)))
#define AS3 __attribute__((address_space(3)))

#define MFMA16(a, b, c) __builtin_amdgcn_mfma_f32_16x16x32_bf16((a), (b), (c), 0, 0, 0)

__device__ __forceinline__ u16 f2b(float f) {
  unsigned u = __float_as_uint(f);
  u = u + 0x7fffu + ((u >> 16) & 1u);
  return (u16)(u >> 16);
}

__device__ __forceinline__ unsigned cvtpk(float lo, float hi) {
  unsigned r;
  asm("v_cvt_pk_bf16_f32 %0, %1, %2" : "=v"(r) : "v"(lo), "v"(hi));
  return r;
}

__device__ __forceinline__ void gload_lds16(const u16* g, u16* l) {
  __builtin_amdgcn_global_load_lds((AS1 unsigned*)(size_t)g, (AS3 unsigned*)l, 16, 0, 0);
}

// ------- fused prep: 6 weight transposes (fp32 [K,N] -> bf16 [N,K]) + LayerNorm1 -------
__global__ __launch_bounds__(256)
void prep_all(const float* __restrict__ Wq, const float* __restrict__ Wk,
              const float* __restrict__ Wv, const float* __restrict__ Wo,
              const float* __restrict__ W1, const float* __restrict__ W2,
              u16* __restrict__ Wqkt, u16* __restrict__ Wvt, u16* __restrict__ Wot,
              u16* __restrict__ W1t, u16* __restrict__ W2t,
              const float* __restrict__ x, const float* __restrict__ alpha,
              const float* __restrict__ beta, u16* __restrict__ xout) {
  __shared__ float t[32][33];
  const int bid = blockIdx.x;
  const int tid = threadIdx.x;
  if (bid < 8192) {  // transpose path
    const float* src;
    u16* dst;
    int K, N, lb;
    if (bid < 1024)      { src = Wq; dst = Wqkt;             K = 1024; N = 1024; lb = bid; }
    else if (bid < 2048) { src = Wk; dst = Wqkt + (1 << 20); K = 1024; N = 1024; lb = bid - 1024; }
    else if (bid < 3072) { src = Wv; dst = Wvt;              K = 1024; N = 1024; lb = bid - 2048; }
    else if (bid < 4096) { src = Wo; dst = Wot;              K = 1024; N = 1024; lb = bid - 3072; }
    else if (bid < 6144) { src = W1; dst = W1t;              K = 1024; N = 2048; lb = bid - 4096; }
    else                 { src = W2; dst = W2t;              K = 2048; N = 1024; lb = bid - 6144; }
    const int nx = N / 32;
    const int n0 = (lb % nx) * 32, k0 = (lb / nx) * 32;
    const int tx = tid & 31, ty = tid >> 5;
#pragma unroll
    for (int i = 0; i < 4; i++) {
      int k = ty + i * 8;
      t[k][tx] = src[(size_t)(k0 + k) * N + n0 + tx];
    }
    __syncthreads();
#pragma unroll
    for (int i = 0; i < 4; i++) {
      int n = ty + i * 8;
      dst[(size_t)(n0 + n) * K + k0 + tx] = f2b(t[tx][n]);
    }
  } else {  // LayerNorm1 path
    const int row = bid - 8192;
    const float4 v = ((const float4*)(x + (size_t)row * DM))[tid];
    float s = v.x + v.y + v.z + v.w;
    float q = v.x * v.x + v.y * v.y + v.z * v.z + v.w * v.w;
#pragma unroll
    for (int off = 1; off < 64; off <<= 1) {
      s += __shfl_xor(s, off);
      q += __shfl_xor(q, off);
    }
    float* ss = &t[0][0];
    float* qq = &t[0][8];
    const int wid = tid >> 6;
    if ((tid & 63) == 0) { ss[wid] = s; qq[wid] = q; }
    __syncthreads();
    s = ss[0] + ss[1] + ss[2] + ss[3];
    q = qq[0] + qq[1] + qq[2] + qq[3];
    const float mean = s * (1.f / DM);
    float var = (q - (float)DM * mean * mean) * (1.f / (DM - 1));
    var = fmaxf(var, 0.f);
    const float inv = 1.f / (sqrtf(var) + 1e-6f);
    const float4 a4 = ((const float4*)alpha)[tid];
    const float4 b4 = ((const float4*)beta)[tid];
    ushort4 o;
    o.x = f2b((v.x - mean) * inv * a4.x + b4.x);
    o.y = f2b((v.y - mean) * inv * a4.y + b4.y);
    o.z = f2b((v.z - mean) * inv * a4.z + b4.z);
    o.w = f2b((v.w - mean) * inv * a4.w + b4.w);
    ((ushort4*)(xout + (size_t)row * DM))[tid] = o;
  }
}

// ---------------- LayerNorm (standalone, for LN2) ----------------
__global__ __launch_bounds__(256)
void ln_kernel(const float* __restrict__ x, const float* __restrict__ alpha,
               const float* __restrict__ beta, u16* __restrict__ out) {
  const int row = blockIdx.x;
  const float4 v = ((const float4*)(x + (size_t)row * DM))[threadIdx.x];
  float s = v.x + v.y + v.z + v.w;
  float q = v.x * v.x + v.y * v.y + v.z * v.z + v.w * v.w;
#pragma unroll
  for (int off = 1; off < 64; off <<= 1) {
    s += __shfl_xor(s, off);
    q += __shfl_xor(q, off);
  }
  __shared__ float ss[4], qq[4];
  const int wid = threadIdx.x >> 6;
  if ((threadIdx.x & 63) == 0) { ss[wid] = s; qq[wid] = q; }
  __syncthreads();
  s = ss[0] + ss[1] + ss[2] + ss[3];
  q = qq[0] + qq[1] + qq[2] + qq[3];
  const float mean = s * (1.f / DM);
  float var = (q - (float)DM * mean * mean) * (1.f / (DM - 1));
  var = fmaxf(var, 0.f);
  const float inv = 1.f / (sqrtf(var) + 1e-6f);
  const float4 a4 = ((const float4*)alpha)[threadIdx.x];
  const float4 b4 = ((const float4*)beta)[threadIdx.x];
  ushort4 o;
  o.x = f2b((v.x - mean) * inv * a4.x + b4.x);
  o.y = f2b((v.y - mean) * inv * a4.y + b4.y);
  o.z = f2b((v.z - mean) * inv * a4.z + b4.z);
  o.w = f2b((v.w - mean) * inv * a4.w + b4.w);
  ((ushort4*)(out + (size_t)row * DM))[threadIdx.x] = o;
}

// ---------------- fused QKV GEMM: QK blocks (mode 0) + V blocks (mode 1) ----------------
__global__ __launch_bounds__(256, 4)
void qkv_gemm(const u16* __restrict__ x2, const u16* __restrict__ Wqkt,
              const u16* __restrict__ Wvt,
              u16* __restrict__ qkb, u16* __restrict__ vtb, float oscale) {
  constexpr int BM = 64, BN = 128, AccM = 2, AccN = 4;
  __shared__ alignas(16) u16 As[3][BM * 32];
  __shared__ alignas(16) u16 Bs[3][BN * 32];
  const int bid = blockIdx.x;
  const int K = DM;
  const u16* A;
  const u16* Bt;
  int bm, bn, mode;
  if (bid < 1024) {
    mode = 0; A = x2; Bt = Wqkt;
    bm = (bid & 63) * BM; bn = (bid >> 6) * BN;
  } else {
    mode = 1; A = Wvt; Bt = x2;
    const int lb = bid - 1024;
    bm = (lb & 15) * BM; bn = (lb >> 4) * BN;
  }
  const int tid = threadIdx.x;
  const int lane = tid & 63, w = tid >> 6;
  const int wm = (w >> 1) * (BM / 2), wn = (w & 1) * (BN / 2);
  const int r = lane & 15, g = lane >> 4;
  const int srow = tid >> 2, skk = (tid & 3) * 8;

  f32x4 acc[AccM][AccN];
#pragma unroll
  for (int i = 0; i < AccM; i++)
#pragma unroll
    for (int j = 0; j < AccN; j++) acc[i][j] = (f32x4){0.f, 0.f, 0.f, 0.f};

  const u16* aP = A + (size_t)(bm + srow) * K + skk;
  const u16* bP = Bt + (size_t)(bn + srow) * K + skk;

  auto stage = [&](int kt, int buf) {
    gload_lds16(aP + kt, &As[buf][0] + w * 512);
    gload_lds16(bP + kt, &Bs[buf][0] + w * 512);
    gload_lds16(bP + (size_t)64 * K + kt, &Bs[buf][0] + w * 512 + 2048);
  };
  auto waitL = [&]() { asm volatile("s_waitcnt vmcnt(3) lgkmcnt(0)" ::: "memory"); };
  auto compute = [&](int buf) {
    bf16x8 af[AccM], bfr[AccN];
#pragma unroll
    for (int i = 0; i < AccM; i++) af[i] = *(const bf16x8*)(&As[buf][(wm + i * 16 + r) * 32 + g * 8]);
#pragma unroll
    for (int j = 0; j < AccN; j++) bfr[j] = *(const bf16x8*)(&Bs[buf][(wn + j * 16 + r) * 32 + g * 8]);
#pragma unroll
    for (int i = 0; i < AccM; i++)
#pragma unroll
      for (int j = 0; j < AccN; j++) acc[i][j] = MFMA16(af[i], bfr[j], acc[i][j]);
  };

  const int NKT = K / 32;
  stage(0, 0);
  stage(32, 1);
  waitL();
  __builtin_amdgcn_s_barrier();
  __builtin_amdgcn_sched_barrier(0);
  for (int it = 0; it < NKT - 2; ++it) {
    stage((it + 2) * 32, (it + 2) % 3);
    compute(it % 3);
    waitL();
    __builtin_amdgcn_s_barrier();
    __builtin_amdgcn_sched_barrier(0);
  }
  compute((NKT - 2) % 3);
  asm volatile("s_waitcnt vmcnt(0) lgkmcnt(0)" ::: "memory");
  __builtin_amdgcn_s_barrier();
  __builtin_amdgcn_sched_barrier(0);
  compute((NKT - 1) % 3);

#pragma unroll
  for (int i = 0; i < AccM; i++)
#pragma unroll
    for (int j = 0; j < AccN; j++)
#pragma unroll
      for (int t = 0; t < 4; t++) {
        const int mg = bm + wm + i * 16 + g * 4 + t;
        const int ng = bn + wn + j * 16 + r;
        const float v = acc[i][j][t];
        if (mode == 0) {
          const int which = ng >> 10, col = ng & 1023;
          const int bb = mg >> 11, ssx = mg & 2047, hh = col >> 6, dd = col & 63;
          const float sc = which ? 1.f : oscale;
          qkb[(size_t)which * (TOK * (size_t)DM) +
              ((size_t)(bb * NH + hh) * SEQ + ssx) * DKK + dd] = f2b(v * sc);
        } else {
          const int hh = mg >> 6, dd = mg & 63, bb = ng >> 11, ssx = ng & 2047;
          vtb[((size_t)(bb * NH + hh) * DKK + dd) * SEQ + ssx] = f2b(v);
        }
      }
}

// ---------------- GEMM (r6 config): triple-buffered LDS, counted vmcnt ----------------
template <int MODE, int BM, int BN>
__global__ __launch_bounds__(256, 4)
void gemm_bt(const u16* __restrict__ A, const u16* __restrict__ Bt,
             int M, int N, int K,
             const float* __restrict__ bias, const float* __restrict__ res,
             void* __restrict__ outp) {
  constexpr int AccM = BM / 32;
  constexpr int AccN = BN / 32;
  constexpr int L = (BM == 128 ? 2 : 1) + (BN == 128 ? 2 : 1);
  __shared__ alignas(16) u16 As[3][BM * 32];
  __shared__ alignas(16) u16 Bs[3][BN * 32];
  const int bm = blockIdx.x * BM, bn = blockIdx.y * BN;
  const int tid = threadIdx.x;
  const int lane = tid & 63, w = tid >> 6;
  const int wm = (w >> 1) * (BM / 2), wn = (w & 1) * (BN / 2);
  const int r = lane & 15, g = lane >> 4;
  const int srow = tid >> 2, skk = (tid & 3) * 8;

  f32x4 acc[AccM][AccN];
#pragma unroll
  for (int i = 0; i < AccM; i++)
#pragma unroll
    for (int j = 0; j < AccN; j++) acc[i][j] = (f32x4){0.f, 0.f, 0.f, 0.f};

  const u16* aP = A + (size_t)(bm + srow) * K + skk;
  const u16* bP = Bt + (size_t)(bn + srow) * K + skk;

  auto stage = [&](int kt, int buf) {
    gload_lds16(aP + kt, &As[buf][0] + w * 512);
    if (BM == 128) gload_lds16(aP + (size_t)64 * K + kt, &As[buf][0] + w * 512 + 2048);
    gload_lds16(bP + kt, &Bs[buf][0] + w * 512);
    if (BN == 128) gload_lds16(bP + (size_t)64 * K + kt, &Bs[buf][0] + w * 512 + 2048);
  };
  auto waitL = [&]() {
    if constexpr (L == 4) asm volatile("s_waitcnt vmcnt(4) lgkmcnt(0)" ::: "memory");
    else if constexpr (L == 3) asm volatile("s_waitcnt vmcnt(3) lgkmcnt(0)" ::: "memory");
    else asm volatile("s_waitcnt vmcnt(2) lgkmcnt(0)" ::: "memory");
  };
  auto compute = [&](int buf) {
    bf16x8 af[AccM], bfr[AccN];
#pragma unroll
    for (int i = 0; i < AccM; i++) af[i] = *(const bf16x8*)(&As[buf][(wm + i * 16 + r) * 32 + g * 8]);
#pragma unroll
    for (int j = 0; j < AccN; j++) bfr[j] = *(const bf16x8*)(&Bs[buf][(wn + j * 16 + r) * 32 + g * 8]);
#pragma unroll
    for (int i = 0; i < AccM; i++)
#pragma unroll
      for (int j = 0; j < AccN; j++) acc[i][j] = MFMA16(af[i], bfr[j], acc[i][j]);
  };

  const int NKT = K / 32;
  stage(0, 0);
  stage(32, 1);
  waitL();
  __builtin_amdgcn_s_barrier();
  __builtin_amdgcn_sched_barrier(0);
  for (int it = 0; it < NKT - 2; ++it) {
    stage((it + 2) * 32, (it + 2) % 3);
    compute(it % 3);
    waitL();
    __builtin_amdgcn_s_barrier();
    __builtin_amdgcn_sched_barrier(0);
  }
  compute((NKT - 2) % 3);
  asm volatile("s_waitcnt vmcnt(0) lgkmcnt(0)" ::: "memory");
  __builtin_amdgcn_s_barrier();
  __builtin_amdgcn_sched_barrier(0);
  compute((NKT - 1) % 3);

#pragma unroll
  for (int i = 0; i < AccM; i++)
#pragma unroll
    for (int j = 0; j < AccN; j++)
#pragma unroll
      for (int t = 0; t < 4; t++) {
        const int mg = bm + wm + i * 16 + g * 4 + t;
        const int ng = bn + wn + j * 16 + r;
        const float v = acc[i][j][t];
        if (MODE == 2) {
          ((float*)outp)[(size_t)mg * N + ng] = res[(size_t)mg * N + ng] + v + bias[ng];
        } else {
          const float hv = v + bias[ng];
          ((u16*)outp)[(size_t)mg * N + ng] = f2b(hv > 0.f ? hv : 0.f);
        }
      }
}

// ---------------- flash attention v13: 8 waves / 128 q-rows, triple-buffered K/V ----------
// T4 counted vmcnt: prefetch distance 2; each wave issues exactly 2 gloads/step;
// end-of-step vmcnt(2) retires tile-(t+1)'s loads, tile-(t+2)'s stay in flight.
__global__ __launch_bounds__(512, 2)
void attn_kernel(const u16* __restrict__ Q, const u16* __restrict__ Kb,
                 const u16* __restrict__ Vt, const float* __restrict__ mask,
                 u16* __restrict__ outc) {
  const int bid = blockIdx.x;
  const int bh = (bid & 7) * 4 + ((bid >> 3) & 3);  // 4 heads per XCD
  const int qt = bid >> 5;                          // 0..15 (128-row q tiles)
  const int b = bh >> 4, h = bh & 15;
  const int tid = threadIdx.x, lane = tid & 63, w = tid >> 6;  // w = 0..7
  const int r = lane & 15, g = lane >> 4;
  const int qbase = qt * 128 + w * 16;
  const u16* Qp = Q + ((size_t)bh * SEQ + qbase) * DKK;
  const u16* Kp = Kb + (size_t)bh * SEQ * DKK;
  const u16* Vp = Vt + (size_t)bh * DKK * SEQ;
  const float* mk = mask + b * SEQ;

  const bf16x8 bq0 = *(const bf16x8*)(Qp + r * DKK + g * 8);
  const bf16x8 bq1 = *(const bf16x8*)(Qp + r * DKK + 32 + g * 8);

  __shared__ __align__(16) u16 Ks[3][64 * 64];  // 24KB
  __shared__ __align__(16) u16 Vs[3][64 * 64];  // 24KB

  // wave w stages rows w*8..w*8+7 of each 64-row tile (1 gload each for K and V)
  const int srow8 = lane >> 3;
  const int sgr = (lane & 7) ^ srow8;  // row key (w*8+srow8)&7 == srow8
  const u16* kSrc = Kp + (size_t)(w * 8 + srow8) * DKK + sgr * 8;
  const u16* vSrc = Vp + (size_t)(w * 8 + srow8) * SEQ + sgr * 8;

  f32x4 o[4];
#pragma unroll
  for (int i = 0; i < 4; i++) o[i] = (f32x4){0.f, 0.f, 0.f, 0.f};
  float lr = 0.f;
  const int keyr = r & 7;

  const int NT = SEQ / 64;

  // prologue: tile 0 -> buf0, tile 1 -> buf1; wait own tile-0 loads; barrier
  gload_lds16(kSrc, &Ks[0][0] + w * 512);
  gload_lds16(vSrc, &Vs[0][0] + w * 512);
  gload_lds16(kSrc + (size_t)64 * DKK, &Ks[1][0] + w * 512);
  gload_lds16(vSrc + 64, &Vs[1][0] + w * 512);
  asm volatile("s_waitcnt vmcnt(2)" ::: "memory");
  __builtin_amdgcn_s_barrier();
  __builtin_amdgcn_sched_barrier(0);

#define ATTN_STEP(IT, BUF, SBUF)                                                   \
  do {                                                                             \
    if ((IT) + 2 < NT) {                                                           \
      const int nsk = ((IT) + 2) * 64;                                             \
      gload_lds16(kSrc + (size_t)nsk * DKK, &Ks[SBUF][0] + w * 512);               \
      gload_lds16(vSrc + nsk, &Vs[SBUF][0] + w * 512);                             \
    }                                                                              \
    f32x4 s[4];                                                                    \
    __builtin_amdgcn_s_setprio(1);                                                 \
    _Pragma("unroll")                                                              \
    for (int ks = 0; ks < 4; ks++) {                                               \
      const bf16x8 ka0 = *(const bf16x8*)&Ks[BUF][(ks * 16 + r) * 64 + ((g ^ keyr) << 3)];        \
      const bf16x8 ka1 = *(const bf16x8*)&Ks[BUF][(ks * 16 + r) * 64 + (((g + 4) ^ keyr) << 3)];  \
      f32x4 z = (f32x4){0.f, 0.f, 0.f, 0.f};                                       \
      z = MFMA16(ka0, bq0, z);                                                     \
      z = MFMA16(ka1, bq1, z);                                                     \
      s[ks] = z;                                                                   \
    }                                                                              \
    __builtin_amdgcn_s_setprio(0);                                                 \
    const int sk = (IT) * 64;                                                      \
    float4 mmv[4];                                                                 \
    _Pragma("unroll")                                                              \
    for (int ks = 0; ks < 4; ks++) mmv[ks] = *(const float4*)(mk + sk + ks * 16 + 4 * g); \
    int ones = 1;                                                                  \
    _Pragma("unroll")                                                              \
    for (int ks = 0; ks < 4; ks++)                                                 \
      ones &= (mmv[ks].x == 1.f) & (mmv[ks].y == 1.f) & (mmv[ks].z == 1.f) & (mmv[ks].w == 1.f); \
    const bool fastm = __all(ones);                                                \
    float p[16];                                                                   \
    float rs = 0.f;                                                                \
    if (fastm) {                                                                   \
      _Pragma("unroll")                                                            \
      for (int ks = 0; ks < 4; ks++) {                                             \
        float e0 = __builtin_amdgcn_exp2f(s[ks][0]);                               \
        float e1 = __builtin_amdgcn_exp2f(s[ks][1]);                               \
        float e2 = __builtin_amdgcn_exp2f(s[ks][2]);                               \
        float e3 = __builtin_amdgcn_exp2f(s[ks][3]);                               \
        p[ks * 4 + 0] = e0; p[ks * 4 + 1] = e1;                                    \
        p[ks * 4 + 2] = e2; p[ks * 4 + 3] = e3;                                    \
        rs += e0 + e1 + e2 + e3;                                                   \
      }                                                                            \
    } else {                                                                       \
      _Pragma("unroll")                                                            \
      for (int ks = 0; ks < 4; ks++) {                                             \
        float pr0 = s[ks][0] * mmv[ks].x, pr1 = s[ks][1] * mmv[ks].y;              \
        float pr2 = s[ks][2] * mmv[ks].z, pr3 = s[ks][3] * mmv[ks].w;              \
        float e0 = (pr0 == 0.f) ? 0.f : __builtin_amdgcn_exp2f(pr0);               \
        float e1 = (pr1 == 0.f) ? 0.f : __builtin_amdgcn_exp2f(pr1);               \
        float e2 = (pr2 == 0.f) ? 0.f : __builtin_amdgcn_exp2f(pr2);               \
        float e3 = (pr3 == 0.f) ? 0.f : __builtin_amdgcn_exp2f(pr3);               \
        p[ks * 4 + 0] = e0; p[ks * 4 + 1] = e1;                                    \
        p[ks * 4 + 2] = e2; p[ks * 4 + 3] = e3;                                    \
        rs += e0 + e1 + e2 + e3;                                                   \
      }                                                                            \
    }                                                                              \
    rs += __shfl_xor(rs, 16);                                                      \
    rs += __shfl_xor(rs, 32);                                                      \
    lr += rs;                                                                      \
    unsigned wk[4][2];                                                             \
    _Pragma("unroll")                                                              \
    for (int ks = 0; ks < 4; ks++) {                                               \
      wk[ks][0] = cvtpk(p[ks * 4 + 0], p[ks * 4 + 1]);                             \
      wk[ks][1] = cvtpk(p[ks * 4 + 2], p[ks * 4 + 3]);                             \
    }                                                                              \
    bf16x8 pa[2];                                                                  \
    _Pragma("unroll")                                                              \
    for (int hh2 = 0; hh2 < 2; hh2++) {                                            \
      union { unsigned u[4]; bf16x8 v; } pu;                                       \
      _Pragma("unroll")                                                            \
      for (int c = 0; c < 4; c++) {                                                \
        const int srcl = r + ((g & 1) * 2 + (c >> 1)) * 16;                        \
        const unsigned lo = __shfl(wk[2 * hh2][c & 1], srcl);                      \
        const unsigned hi = __shfl(wk[2 * hh2 + 1][c & 1], srcl);                  \
        pu.u[c] = (g < 2) ? lo : hi;                                               \
      }                                                                            \
      pa[hh2] = pu.v;                                                              \
    }                                                                              \
    __builtin_amdgcn_s_setprio(1);                                                 \
    _Pragma("unroll")                                                              \
    for (int dc = 0; dc < 4; dc++) {                                               \
      const int vr = dc * 16 + r;                                                  \
      const bf16x8 bv0 = *(const bf16x8*)&Vs[BUF][vr * 64 + ((g ^ keyr) << 3)];    \
      const bf16x8 bv1 = *(const bf16x8*)&Vs[BUF][vr * 64 + (((g + 4) ^ keyr) << 3)]; \
      o[dc] = MFMA16(pa[0], bv0, o[dc]);                                           \
      o[dc] = MFMA16(pa[1], bv1, o[dc]);                                           \
    }                                                                              \
    __builtin_amdgcn_s_setprio(0);                                                 \
    if ((IT) + 2 < NT) {                                                           \
      asm volatile("s_waitcnt vmcnt(2) lgkmcnt(0)" ::: "memory");                  \
    } else {                                                                       \
      asm volatile("s_waitcnt vmcnt(0) lgkmcnt(0)" ::: "memory");                  \
    }                                                                              \
    __builtin_amdgcn_s_barrier();                                                  \
    __builtin_amdgcn_sched_barrier(0);                                             \
  } while (0)

  // NT = 32: 30 steps unrolled by 3 (compile-time buffers), then 2 tail steps.
  for (int it = 0; it < 30; it += 3) {
    ATTN_STEP(it, 0, 2);
    ATTN_STEP(it + 1, 1, 0);
    ATTN_STEP(it + 2, 2, 1);
  }
  ATTN_STEP(30, 0, 2);
  ATTN_STEP(31, 1, 0);
#undef ATTN_STEP

  float lq[4];
#pragma unroll
  for (int t = 0; t < 4; t++) lq[t] = __shfl(lr, 4 * g + t);
#pragma unroll
  for (int dc = 0; dc < 4; dc++)
#pragma unroll
    for (int t = 0; t < 4; t++) {
      const int srow_g = qbase + g * 4 + t;
      outc[((size_t)(b * SEQ + srow_g)) * DM + h * DKK + dc * 16 + r] = f2b(o[dc][t] / lq[t]);
    }
}

extern "C" void kernel_launch(void* const* d_in, const int* in_sizes, int n_in,
                              void* d_out, int out_size, void* d_ws, size_t ws_size,
                              hipStream_t stream) {
  const float* x    = (const float*)d_in[0];
  const float* mask = (const float*)d_in[1];
  const float* Wq   = (const float*)d_in[2];
  const float* Wk   = (const float*)d_in[3];
  const float* Wv   = (const float*)d_in[4];
  const float* Wo   = (const float*)d_in[5];
  const float* bo   = (const float*)d_in[6];
  const float* W1   = (const float*)d_in[7];
  const float* b1   = (const float*)d_in[8];
  const float* W2   = (const float*)d_in[9];
  const float* b2   = (const float*)d_in[10];
  const float* l1a  = (const float*)d_in[11];
  const float* l1b  = (const float*)d_in[12];
  const float* l2a  = (const float*)d_in[13];
  const float* l2b  = (const float*)d_in[14];

  char* wsb = (char*)d_ws;
  u16* Wqkt = (u16*)(wsb + (0ull << 20));
  u16* Wvt  = (u16*)(wsb + (4ull << 20));
  u16* Wot  = (u16*)(wsb + (6ull << 20));
  u16* W1t  = (u16*)(wsb + (8ull << 20));
  u16* W2t  = (u16*)(wsb + (12ull << 20));
  u16* x2   = (u16*)(wsb + (16ull << 20));
  u16* qkb  = (u16*)(wsb + (24ull << 20));
  u16* vtb  = (u16*)(wsb + (40ull << 20));
  float* x1 = (float*)(wsb + (48ull << 20));
  u16* concat = x2;
  u16* x2b = qkb;
  u16* hb  = (u16*)(wsb + (32ull << 20));

  const float qscale = 0.125f * 1.4426950408889634f;

  prep_all<<<dim3(12288), 256, 0, stream>>>(Wq, Wk, Wv, Wo, W1, W2,
                                            Wqkt, Wvt, Wot, W1t, W2t,
                                            x, l1a, l1b, x2);

  qkv_gemm<<<dim3(1536), 256, 0, stream>>>(x2, Wqkt, Wvt, qkb, vtb, qscale);

  attn_kernel<<<dim3(512), 512, 0, stream>>>(qkb, qkb + (size_t)TOK * DM, vtb, mask, concat);

  gemm_bt<2, 64, 64><<<dim3(TOK / 64, DM / 64), 256, 0, stream>>>(
      concat, Wot, TOK, DM, DM, bo, x, x1);

  ln_kernel<<<TOK, 256, 0, stream>>>(x1, l2a, l2b, x2b);

  gemm_bt<3, 64, 128><<<dim3(TOK / 64, DFF / 128), 256, 0, stream>>>(
      x2b, W1t, TOK, DFF, DM, b1, nullptr, hb);
  gemm_bt<2, 64, 64><<<dim3(TOK / 64, DM / 64), 256, 0, stream>>>(
      hb, W2t, TOK, DM, DFF, b2, x1, (float*)d_out);
}